// Round 3
// baseline (346.849 us; speedup 1.0000x reference)
//
#include <hip/hip_runtime.h>
#include <stdint.h>

// Correlation1dCost: out[b,d,y,x] = leaky_relu_0.1( sum_c f1[b,c,y,x]*f2[b,c,y,x+d-47] )
// B=8, C=128, H=128, W=256, ND=48. Zero contribution where x+d-47 < 0.
//
// R3: R1/R2 showed the compiler scalarizes float4 LDS accesses into
// ds_read_b32 (lane-stride 4 words -> 8-way bank conflict, 5.03e7 conflict
// cycles) while squeezing to 60-64 VGPRs to chase 8 waves/EU. Fix:
//  (a) inline-asm ds_read_b128 / ds_write_b128 — can't be scalarized;
//  (b) amdgpu_waves_per_eu(2,4) — caps occupancy target, 128-VGPR budget.

typedef float f32x4 __attribute__((ext_vector_type(4)));

#define Bn 8
#define Cn 128
#define Hn 128
#define Wn 256
#define ND 48
#define PAD 48           // LDS f2 buffer starts at shift index -48 (16B aligned)
#define F2LEN 304        // covers shifted x in [-48, 255]
#define CC 8             // channels staged per iteration
#define TD 12            // d's per thread
// thread layout: 64 x-groups (4 x each) x 4 d-groups (12 d each) = 256 threads

// Low 32 bits of a generic pointer to LDS == ds byte offset (gfx9+ aperture
// is 4GB-aligned; addrspacecast builds {aperture_hi, offset32}).
__device__ __forceinline__ unsigned lds_off(const void* p) {
    return (unsigned)(uintptr_t)p;
}

__device__ __forceinline__ void lds_write_b128(unsigned off, f32x4 v) {
    asm volatile("ds_write_b128 %0, %1" :: "v"(off), "v"(v) : "memory");
}

__global__ __launch_bounds__(256)
__attribute__((amdgpu_waves_per_eu(2, 4)))
void corr1d_kernel(const float* __restrict__ f1,
                   const float* __restrict__ f2,
                   float* __restrict__ out)
{
    __shared__ float s1[CC][Wn];     // 8 KB
    __shared__ float s2[CC][F2LEN];  // 9.5 KB

    const int y   = blockIdx.x;      // 0..127
    const int b   = blockIdx.y;      // 0..7
    const int tid = threadIdx.x;
    const int i   = tid & 63;        // x-group: x = 4*i .. 4*i+3
    const int j   = tid >> 6;        // d-group: d = 12*j .. 12*j+11

    const unsigned s1b = lds_off(&s1[0][0]);
    const unsigned s2b = lds_off(&s2[0][0]);
    // per-thread read bases (bytes): s1 at word i*4; s2 at word i*4 + j*12
    const unsigned off1_0 = s1b + (unsigned)(i * 16);
    const unsigned off2_0 = s2b + (unsigned)(i * 16 + j * 48);

    const size_t chw = (size_t)Hn * Wn;                 // channel stride
    const float* f1base = f1 + ((size_t)b * Cn * Hn + y) * Wn;
    const float* f2base = f2 + ((size_t)b * Cn * Hn + y) * Wn;

    float acc[4][TD];
    #pragma unroll
    for (int xr = 0; xr < 4; ++xr)
        #pragma unroll
        for (int dr = 0; dr < TD; ++dr) acc[xr][dr] = 0.f;

    for (int c0 = 0; c0 < Cn; c0 += CC) {
        // ---- stage f1: CC rows x 64 float4 = 512 float4, 2 per thread ----
        #pragma unroll
        for (int rep = 0; rep < 2; ++rep) {
            int lin = tid + rep * 256;          // [0,512)
            int cl  = lin >> 6;
            int p4  = lin & 63;
            f32x4 v = *(const f32x4*)(f1base + (size_t)(c0 + cl) * chw + p4 * 4);
            lds_write_b128(s1b + (unsigned)((cl * Wn + p4 * 4) * 4), v);
        }
        // ---- stage f2: CC rows x 76 float4 (first 12 are the zero pad) ----
        for (int lin = tid; lin < CC * 76; lin += 256) {
            int cl = lin / 76;
            int p4 = lin - cl * 76;
            int s4 = p4 * 4 - PAD;              // shifted-x of first float
            f32x4 v = {0.f, 0.f, 0.f, 0.f};
            if (s4 >= 0)
                v = *(const f32x4*)(f2base + (size_t)(c0 + cl) * chw + s4);
            lds_write_b128(s2b + (unsigned)((cl * F2LEN + p4 * 4) * 4), v);
        }
        __syncthreads();

        // ---- compute: per channel, 5 forced ds_read_b128, 48 FMAs ----
        unsigned off1 = off1_0;
        unsigned off2 = off2_0;
        #pragma unroll
        for (int cc = 0; cc < CC; ++cc) {
            f32x4 av, q0, q1, q2, q3;
            asm volatile(
                "ds_read_b128 %0, %5\n\t"
                "ds_read_b128 %1, %6\n\t"
                "ds_read_b128 %2, %6 offset:16\n\t"
                "ds_read_b128 %3, %6 offset:32\n\t"
                "ds_read_b128 %4, %6 offset:48\n\t"
                "s_waitcnt lgkmcnt(0)"
                : "=&v"(av), "=&v"(q0), "=&v"(q1), "=&v"(q2), "=&v"(q3)
                : "v"(off1), "v"(off2));
            off1 += Wn * 4;        // next channel row in s1 (1024 B)
            off2 += F2LEN * 4;     // next channel row in s2 (1216 B)

            float a[4]  = {av[0], av[1], av[2], av[3]};
            float q[16] = {q0[0], q0[1], q0[2], q0[3],
                           q1[0], q1[1], q1[2], q1[3],
                           q2[0], q2[1], q2[2], q2[3],
                           q3[0], q3[1], q3[2], q3[3]};
            // out x = 4i+xr, d = 12j+dr -> shifted idx (4i+xr)+(12j+dr)-47,
            // buffer-relative = xr+dr+1  (buffer starts at word -48)
            #pragma unroll
            for (int xr = 0; xr < 4; ++xr)
                #pragma unroll
                for (int dr = 0; dr < TD; ++dr)
                    acc[xr][dr] += a[xr] * q[xr + dr + 1];
        }
        __syncthreads();
    }

    // ---- epilogue: leaky_relu + float4 stores (contiguous per wave) ----
    #pragma unroll
    for (int dr = 0; dr < TD; ++dr) {
        int d = j * TD + dr;
        float vx[4];
        #pragma unroll
        for (int xr = 0; xr < 4; ++xr) {
            float t = acc[xr][dr];
            vx[xr] = t >= 0.f ? t : 0.1f * t;
        }
        float4 v = make_float4(vx[0], vx[1], vx[2], vx[3]);
        *(float4*)(out + (((size_t)(b * ND + d) * Hn + y) * Wn + i * 4)) = v;
    }
}

extern "C" void kernel_launch(void* const* d_in, const int* in_sizes, int n_in,
                              void* d_out, int out_size, void* d_ws, size_t ws_size,
                              hipStream_t stream) {
    const float* feat1 = (const float*)d_in[0];
    const float* feat2 = (const float*)d_in[1];
    float* out = (float*)d_out;
    dim3 grid(Hn, Bn);   // blockIdx.x = y, blockIdx.y = b
    dim3 block(256);
    corr1d_kernel<<<grid, block, 0, stream>>>(feat1, feat2, out);
}

// Round 4
// 322.161 us; speedup vs baseline: 1.0766x; 1.0766x over previous
//
#include <hip/hip_runtime.h>
#include <stdint.h>

// Correlation1dCost: out[b,d,y,x] = leaky_relu_0.1( sum_c f1[b,c,y,x]*f2[b,c,y,x+d-47] )
// B=8, C=128, H=128, W=256, ND=48. Zero contribution where x+d-47 < 0.
//
// R4: latency-bound fix. f1 read straight from global (L1-broadcast across the
// 4 j-replicas, no LDS round-trip). f2 staged in LDS with a register-prefetch
// pipeline (tile k+1 globals in flight during tile k compute). Zero pad
// written once. CC=16 -> 8 barrier pairs. LDS ops pinned as b128 via asm
// (R1/R2: compiler scalarized float4 LDS ops into stride-4 ds_read_b32,
// 8-way conflicts; R3: fixed conflicts but serialized staging).

typedef float f32x4 __attribute__((ext_vector_type(4)));

#define Bn 8
#define Cn 128
#define Hn 128
#define Wn 256
#define ND 48
#define F2Q 76           // float4s per s2 row: 12 pad (words -48..-1) + 64 data
#define CC 16            // channels staged per iteration
#define NIT (Cn / CC)    // 8 iterations
#define TD 12            // d's per thread
// thread layout: 64 x-groups (4 x each) x 4 d-groups (12 d each) = 256 threads

__device__ __forceinline__ unsigned lds_off(const void* p) {
    return (unsigned)(uintptr_t)p;
}

__device__ __forceinline__ void lds_write_b128(unsigned off, f32x4 v) {
    asm volatile("ds_write_b128 %0, %1" :: "v"(off), "v"(v) : "memory");
}

__global__ __launch_bounds__(256)
__attribute__((amdgpu_waves_per_eu(2, 4)))
void corr1d_kernel(const float* __restrict__ f1,
                   const float* __restrict__ f2,
                   float* __restrict__ out)
{
    __shared__ f32x4 s2v[CC][F2Q];   // 19456 B

    const int y   = blockIdx.x;      // 0..127
    const int b   = blockIdx.y;      // 0..7
    const int tid = threadIdx.x;
    const int i   = tid & 63;        // x-group: x = 4*i .. 4*i+3
    const int j   = tid >> 6;        // d-group: d = 12*j .. 12*j+11

    const unsigned s2b   = lds_off(&s2v[0][0]);
    const unsigned offq0 = s2b + (unsigned)((i + 3 * j) * 16);  // q window (16B aligned)

    const size_t chw = (size_t)Hn * Wn;
    const float* f1base = f1 + ((size_t)b * Cn * Hn + y) * Wn;
    const float* f2base = f2 + ((size_t)b * Cn * Hn + y) * Wn;

    // staging assignment: 4 slots/thread, lin = tid + t*256 in [0,1024)
    const int scl[4] = { (tid +   0) >> 6, (tid + 256) >> 6,
                         (tid + 512) >> 6, (tid + 768) >> 6 };
    const int sp    = tid & 63;      // data float4 within row (word 4*sp)
    unsigned swoff[4];
    #pragma unroll
    for (int t = 0; t < 4; ++t)
        swoff[t] = s2b + (unsigned)((scl[t] * F2Q + 12 + sp) * 16);

    // ---- write the always-zero pad region once (rows x float4 0..11) ----
    if ((tid & 15) < 12) {
        f32x4 z = {0.f, 0.f, 0.f, 0.f};
        lds_write_b128(s2b + (unsigned)(((tid >> 4) * F2Q + (tid & 15)) * 16), z);
    }

    float acc[4][TD];
    #pragma unroll
    for (int xr = 0; xr < 4; ++xr)
        #pragma unroll
        for (int dr = 0; dr < TD; ++dr) acc[xr][dr] = 0.f;

    // ---- prefetch tile 0 ----
    f32x4 g[4];
    #pragma unroll
    for (int t = 0; t < 4; ++t)
        g[t] = *(const f32x4*)(f2base + (size_t)scl[t] * chw + sp * 4);

    for (int it = 0; it < NIT; ++it) {
        const int c0 = it * CC;
        __syncthreads();                       // prior compute reads done
        #pragma unroll
        for (int t = 0; t < 4; ++t)
            lds_write_b128(swoff[t], g[t]);
        __syncthreads();

        if (it + 1 < NIT) {                    // issue tile it+1 loads now
            #pragma unroll
            for (int t = 0; t < 4; ++t)
                g[t] = *(const f32x4*)(f2base + (size_t)(c0 + CC + scl[t]) * chw + sp * 4);
        }

        // ---- compute: per channel, 1 global f1 float4 + 4 ds_read_b128 ----
        const float* f1p = f1base + (size_t)c0 * chw + i * 4;
        unsigned offq = offq0;
        #pragma unroll 4
        for (int cc = 0; cc < CC; ++cc) {
            f32x4 av = *(const f32x4*)(f1p + (size_t)cc * chw);
            f32x4 q0, q1, q2, q3;
            asm volatile(
                "ds_read_b128 %0, %4\n\t"
                "ds_read_b128 %1, %4 offset:16\n\t"
                "ds_read_b128 %2, %4 offset:32\n\t"
                "ds_read_b128 %3, %4 offset:48\n\t"
                "s_waitcnt lgkmcnt(0)"
                : "=&v"(q0), "=&v"(q1), "=&v"(q2), "=&v"(q3)
                : "v"(offq));
            offq += F2Q * 16;                  // next channel row (1216 B)

            float a[4]  = {av[0], av[1], av[2], av[3]};
            float q[16] = {q0[0], q0[1], q0[2], q0[3],
                           q1[0], q1[1], q1[2], q1[3],
                           q2[0], q2[1], q2[2], q2[3],
                           q3[0], q3[1], q3[2], q3[3]};
            // out x = 4i+xr, d = 12j+dr -> buffer word 4i+12j + (xr+dr+1)
            #pragma unroll
            for (int xr = 0; xr < 4; ++xr)
                #pragma unroll
                for (int dr = 0; dr < TD; ++dr)
                    acc[xr][dr] += a[xr] * q[xr + dr + 1];
        }
    }

    // ---- epilogue: leaky_relu + float4 stores (contiguous per wave) ----
    #pragma unroll
    for (int dr = 0; dr < TD; ++dr) {
        int d = j * TD + dr;
        float vx[4];
        #pragma unroll
        for (int xr = 0; xr < 4; ++xr) {
            float t = acc[xr][dr];
            vx[xr] = t >= 0.f ? t : 0.1f * t;
        }
        float4 v = make_float4(vx[0], vx[1], vx[2], vx[3]);
        *(float4*)(out + (((size_t)(b * ND + d) * Hn + y) * Wn + i * 4)) = v;
    }
}

extern "C" void kernel_launch(void* const* d_in, const int* in_sizes, int n_in,
                              void* d_out, int out_size, void* d_ws, size_t ws_size,
                              hipStream_t stream) {
    const float* feat1 = (const float*)d_in[0];
    const float* feat2 = (const float*)d_in[1];
    float* out = (float*)d_out;
    dim3 grid(Hn, Bn);   // blockIdx.x = y, blockIdx.y = b
    dim3 block(256);
    corr1d_kernel<<<grid, block, 0, stream>>>(feat1, feat2, out);
}